// Round 1
// baseline (302.364 us; speedup 1.0000x reference)
//
#include <hip/hip_runtime.h>
#include <hip/hip_bf16.h>
#include <math.h>

typedef __bf16 bf16_t;
typedef bf16_t bf16x8 __attribute__((ext_vector_type(8)));
typedef float f32x4 __attribute__((ext_vector_type(4)));

// ---------------- async global->LDS (16B per lane) ----------------
__device__ __forceinline__ void g2l16(const bf16_t* g, bf16_t* l) {
    __builtin_amdgcn_global_load_lds(
        (const __attribute__((address_space(1))) void*)g,
        (__attribute__((address_space(3))) void*)l, 16, 0, 0);
}

// ---------------- dtype probe: 0 = bf16 storage, 1 = fp32 storage ----------------
// fp32 data viewed as bf16: low-half slots have uniform-random exponent bits ->
// ~47% have exp>=0x88 (|v|>=2^9). Genuine bf16 N(0,1): exp<=0x81, count 0.
__global__ void probe_dtype(const unsigned short* x, int* flag) {
    __shared__ int bad;
    if (threadIdx.x == 0) bad = 0;
    __syncthreads();
    int cnt = 0;
    for (int i = threadIdx.x; i < 8192; i += 256) {
        int e = (x[i] >> 7) & 0xFF;
        if (e >= 0x88) cnt++;
    }
    atomicAdd(&bad, cnt);
    __syncthreads();
    if (threadIdx.x == 0) flag[0] = (bad > 4) ? 1 : 0;
}

// ---------------- x -> bf16 workspace copy/convert ----------------
__global__ void prep_x(const void* __restrict__ xin, bf16_t* __restrict__ xb,
                       int n8, const int* __restrict__ flag) {
    const int f32 = *flag;
    int t = blockIdx.x * blockDim.x + threadIdx.x;
    int stride = gridDim.x * blockDim.x;
    if (f32) {
        const float4* p = (const float4*)xin;
        for (int i = t; i < n8; i += stride) {
            float4 a = p[2 * i], b = p[2 * i + 1];
            bf16x8 o;
            o[0] = (bf16_t)a.x; o[1] = (bf16_t)a.y; o[2] = (bf16_t)a.z; o[3] = (bf16_t)a.w;
            o[4] = (bf16_t)b.x; o[5] = (bf16_t)b.y; o[6] = (bf16_t)b.z; o[7] = (bf16_t)b.w;
            *(bf16x8*)(xb + (size_t)i * 8) = o;
        }
    } else {
        const uint4* p = (const uint4*)xin;
        uint4* q = (uint4*)xb;
        for (int i = t; i < n8; i += stride) q[i] = p[i];
    }
}

// ---------------- bias -> fp32 ----------------
__global__ void cvt_f32(const void* __restrict__ in, float* __restrict__ out,
                        int n, const int* __restrict__ flag) {
    const int f32 = *flag;
    int t = blockIdx.x * blockDim.x + threadIdx.x;
    if (t < n) out[t] = f32 ? ((const float*)in)[t] : (float)(((const bf16_t*)in)[t]);
}

// ---------------- PQ dequant: W[r, c*sub+j] = cb[c, idx[c,r], j], C=8, K=256 ----
__global__ void dequant_w(const void* __restrict__ cb, const int* __restrict__ idx,
                          bf16_t* __restrict__ W, int rows, int sub, int logsub,
                          const int* __restrict__ flag) {
    const int f32 = *flag;
    int t = blockIdx.x * blockDim.x + threadIdx.x;
    int stride = gridDim.x * blockDim.x;
    const int total = rows * sub;         // 8-elem groups (width = 8*sub)
    for (int i = t; i < total; i += stride) {
        int r = i >> logsub;              // row (i / sub)
        int g = i & (sub - 1);            // group in row
        int col = g << 3;                 // 0 .. 8*sub-1
        int c = col >> logsub;            // codebook index
        int j = col & (sub - 1);
        int code = idx[c * rows + r];
        size_t src = ((size_t)(c * 256 + code) << logsub) + j;
        bf16x8 o;
        if (f32) {
            const float* s = (const float*)cb + src;
            float4 a = *(const float4*)s;
            float4 b = *(const float4*)(s + 4);
            o[0] = (bf16_t)a.x; o[1] = (bf16_t)a.y; o[2] = (bf16_t)a.z; o[3] = (bf16_t)a.w;
            o[4] = (bf16_t)b.x; o[5] = (bf16_t)b.y; o[6] = (bf16_t)b.z; o[7] = (bf16_t)b.w;
        } else {
            o = *(const bf16x8*)((const bf16_t*)cb + src);
        }
        *(bf16x8*)(W + (size_t)r * ((size_t)sub << 3) + col) = o;
    }
}

// ---------------- GEMM: C[m,n] = sum_k A[m,k]*Bw[n,k] + bias[n] (opt gelu) ------
// m97 recipe: 128x128 tile, BK=32, 4 waves 2x2, each wave 4x4 of 16x16x32 MFMA,
// global_load_lds width=16 staging (LDS layout contiguous in lane order).
template <bool GELU, bool DYNOUT>
__global__ __launch_bounds__(256, 2)
void gemm_bt(const bf16_t* __restrict__ A, const bf16_t* __restrict__ Bw,
             const float* __restrict__ bias,
             bf16_t* __restrict__ obf, float* __restrict__ of32,
             int M, int N, int K, const int* __restrict__ flag) {
    __shared__ __attribute__((aligned(16))) bf16_t sA[128 * 32];
    __shared__ __attribute__((aligned(16))) bf16_t sB[128 * 32];

    const int tid = threadIdx.x;
    const int bm = blockIdx.y << 7;
    const int bn = blockIdx.x << 7;

    // staging: thread t loads 8 bf16 (16B); pass0 rows 0..63, pass1 rows 64..127
    const int srow = tid >> 2;
    const int scol = (tid & 3) << 3;
    const bf16_t* gA = A + (size_t)(bm + srow) * K + scol;
    const bf16_t* gB = Bw + (size_t)(bn + srow) * K + scol;
    bf16_t* lA = sA + tid * 8;
    bf16_t* lB = sB + tid * 8;
    const size_t rowskip = (size_t)64 * K;

    const int lane = tid & 63;
    const int wave = tid >> 6;
    const int quad = lane >> 4;
    const int lr = lane & 15;
    const int wm = (wave & 1) << 6;
    const int wn = (wave >> 1) << 6;

    const bf16x8* pA = (const bf16x8*)(sA + (wm + lr) * 32 + quad * 8);
    const bf16x8* pB = (const bf16x8*)(sB + (wn + lr) * 32 + quad * 8);

    f32x4 acc[4][4] = {};

    for (int k0 = 0; k0 < K; k0 += 32) {
        g2l16(gA + k0, lA);
        g2l16(gA + rowskip + k0, lA + 2048);
        g2l16(gB + k0, lB);
        g2l16(gB + rowskip + k0, lB + 2048);
        __syncthreads();   // compiler drains vmcnt(0) before s_barrier

        bf16x8 af[4], bf[4];
#pragma unroll
        for (int i = 0; i < 4; ++i) {
            af[i] = pA[i * 64];   // +16 rows = 64 bf16x8 units
            bf[i] = pB[i * 64];
        }
#pragma unroll
        for (int mi = 0; mi < 4; ++mi)
#pragma unroll
            for (int ni = 0; ni < 4; ++ni)
                acc[mi][ni] = __builtin_amdgcn_mfma_f32_16x16x32_bf16(
                    af[mi], bf[ni], acc[mi][ni], 0, 0, 0);
        __syncthreads();
    }

    const int outf32 = DYNOUT ? *flag : 0;
#pragma unroll
    for (int mi = 0; mi < 4; ++mi) {
#pragma unroll
        for (int ni = 0; ni < 4; ++ni) {
            const int n = bn + wn + ni * 16 + lr;
            const float bs = bias[n];
            f32x4 v = acc[mi][ni];
#pragma unroll
            for (int r = 0; r < 4; ++r) {
                const int m = bm + wm + mi * 16 + quad * 4 + r;
                float val = v[r] + bs;
                if (GELU) val = 0.5f * val * (1.0f + erff(val * 0.70710678118654752f));
                const size_t o = (size_t)m * N + n;
                if (DYNOUT) {
                    if (outf32) of32[o] = val;
                    else        obf[o] = (bf16_t)val;
                } else {
                    obf[o] = (bf16_t)val;
                }
            }
        }
    }
}

// ---------------- launch ----------------
extern "C" void kernel_launch(void* const* d_in, const int* in_sizes, int n_in,
                              void* d_out, int out_size, void* d_ws, size_t ws_size,
                              hipStream_t stream) {
    const void* x   = d_in[0];
    const void* cb1 = d_in[1];
    const int*  idx1 = (const int*)d_in[2];
    const void* b1  = d_in[3];
    const void* cb2 = d_in[4];
    const int*  idx2 = (const int*)d_in[5];
    const void* b2  = d_in[6];

    const int D = 1024, H = 4096;
    const int M = in_sizes[0] / D;     // 8192

    char* ws = (char*)d_ws;
    bf16_t* xb  = (bf16_t*)ws;                                   // M*D bf16 (16 MB)
    bf16_t* w1b = (bf16_t*)(ws + (size_t)M * D * 2);             // H*D bf16 (8 MB)
    bf16_t* hb  = (bf16_t*)((char*)w1b + (size_t)H * D * 2);     // M*H bf16 (64 MB)
    bf16_t* w2b = (bf16_t*)((char*)hb + (size_t)M * H * 2);      // D*H bf16 (8 MB)
    float*  b1f = (float*)((char*)w2b + (size_t)D * H * 2);      // H f32
    float*  b2f = b1f + H;                                       // D f32
    int*    flag = (int*)(b2f + D);

    probe_dtype<<<1, 256, 0, stream>>>((const unsigned short*)x, flag);
    prep_x<<<1024, 256, 0, stream>>>(x, xb, M * D / 8, flag);
    cvt_f32<<<(H + 255) / 256, 256, 0, stream>>>(b1, b1f, H, flag);
    cvt_f32<<<(D + 255) / 256, 256, 0, stream>>>(b2, b2f, D, flag);
    dequant_w<<<1024, 256, 0, stream>>>(cb1, idx1, w1b, H, 128, 7, flag);
    dequant_w<<<1024, 256, 0, stream>>>(cb2, idx2, w2b, D, 512, 9, flag);

    dim3 g1(H / 128, M / 128);   // (32, 64)
    gemm_bt<true, false><<<g1, 256, 0, stream>>>(xb, w1b, b1f, hb, nullptr, M, H, D, flag);

    dim3 g2(D / 128, M / 128);   // (8, 64)
    gemm_bt<false, true><<<g2, 256, 0, stream>>>(hb, w2b, b2f, (bf16_t*)d_out, (float*)d_out, M, D, H, flag);
}

// Round 2
// 296.108 us; speedup vs baseline: 1.0211x; 1.0211x over previous
//
#include <hip/hip_runtime.h>
#include <hip/hip_bf16.h>
#include <math.h>

typedef __bf16 bf16_t;
typedef bf16_t bf16x8 __attribute__((ext_vector_type(8)));
typedef float f32x4 __attribute__((ext_vector_type(4)));

// ---------------- async global->LDS (16B per lane) ----------------
__device__ __forceinline__ void g2l16(const bf16_t* g, bf16_t* l) {
    __builtin_amdgcn_global_load_lds(
        (const __attribute__((address_space(1))) void*)g,
        (__attribute__((address_space(3))) void*)l, 16, 0, 0);
}

// ---------------- fused prep: probe + x->bf16 + dequant W1/W2 + biases ---------
// Each block independently probes x's storage dtype (fp32 data viewed as u16:
// ~47% of low-half words have bf16-exponent >= 0x88; genuine bf16 N(0,1): none),
// then grid-strides over a unified task index space. One kernel instead of six.
__global__ void prep_all(const void* __restrict__ x,
                         const void* __restrict__ cb1, const int* __restrict__ idx1,
                         const void* __restrict__ b1,
                         const void* __restrict__ cb2, const int* __restrict__ idx2,
                         const void* __restrict__ b2,
                         bf16_t* __restrict__ xb, bf16_t* __restrict__ w1b,
                         bf16_t* __restrict__ w2b, float* __restrict__ b1f,
                         float* __restrict__ b2f, int* __restrict__ flag, int M) {
    __shared__ int s_bad;
    if (threadIdx.x == 0) s_bad = 0;
    __syncthreads();
    const unsigned short* xu = (const unsigned short*)x;
    int cnt = 0;
    for (int i = threadIdx.x; i < 8192; i += 256)
        cnt += (((xu[i] >> 7) & 0xFF) >= 0x88);
    atomicAdd(&s_bad, cnt);
    __syncthreads();
    const int f32 = (s_bad > 4);
    if (blockIdx.x == 0 && threadIdx.x == 0) flag[0] = f32;  // for GEMM2 epilogue

    const int T0 = (M * 1024) / 8;      // x 8-elem groups
    const int T1 = 4096 * 128;          // W1 groups (rows=4096, width 1024)
    const int T2 = 1024 * 512;          // W2 groups (rows=1024, width 4096)
    const int TB = (4096 + 1024) / 8;   // bias groups
    const int total = T0 + T1 + T2 + TB;
    const int t = blockIdx.x * 256 + threadIdx.x;
    const int stride = gridDim.x * 256;

    for (int i = t; i < total; i += stride) {
        if (i < T0) {
            // ---- x -> bf16 ----
            bf16x8 o;
            if (f32) {
                const float4* p = (const float4*)x;
                float4 a = p[2 * i], b = p[2 * i + 1];
                o[0] = (bf16_t)a.x; o[1] = (bf16_t)a.y; o[2] = (bf16_t)a.z; o[3] = (bf16_t)a.w;
                o[4] = (bf16_t)b.x; o[5] = (bf16_t)b.y; o[6] = (bf16_t)b.z; o[7] = (bf16_t)b.w;
            } else {
                o = ((const bf16x8*)x)[i];
            }
            *(bf16x8*)(xb + (size_t)i * 8) = o;
        } else if (i < T0 + T1 + T2) {
            // ---- PQ dequant (C=8, K=256) ----
            int g2 = (i >= T0 + T1);
            int ii = g2 ? (i - T0 - T1) : (i - T0);
            int rows = g2 ? 1024 : 4096;
            int logsub = g2 ? 9 : 7;     // subvector length = width/8
            int sub = 1 << logsub;       // == groups per row here (C=8)
            const int* idx = g2 ? idx2 : idx1;
            const void* cb = g2 ? cb2 : cb1;
            bf16_t* W = g2 ? w2b : w1b;
            int r = ii >> logsub;
            int col = (ii & (sub - 1)) << 3;
            int c = col >> logsub;
            int j = col & (sub - 1);
            int code = idx[c * rows + r];
            size_t src = ((size_t)(c * 256 + code) << logsub) + j;
            bf16x8 o;
            if (f32) {
                const float* s = (const float*)cb + src;
                float4 a = *(const float4*)s;
                float4 b = *(const float4*)(s + 4);
                o[0] = (bf16_t)a.x; o[1] = (bf16_t)a.y; o[2] = (bf16_t)a.z; o[3] = (bf16_t)a.w;
                o[4] = (bf16_t)b.x; o[5] = (bf16_t)b.y; o[6] = (bf16_t)b.z; o[7] = (bf16_t)b.w;
            } else {
                o = *(const bf16x8*)((const bf16_t*)cb + src);
            }
            *(bf16x8*)(W + (size_t)r * ((size_t)sub << 3) + col) = o;
        } else {
            // ---- biases -> fp32 ----
            int g = i - (T0 + T1 + T2);
#pragma unroll
            for (int j = 0; j < 8; ++j) {
                int e = g * 8 + j;
                float v;
                const void* src = (e < 4096) ? b1 : b2;
                int k = (e < 4096) ? e : e - 4096;
                v = f32 ? ((const float*)src)[k] : (float)(((const bf16_t*)src)[k]);
                if (e < 4096) b1f[k] = v; else b2f[k] = v;
            }
        }
    }
}

// ---------------- GEMM: C[m,n] = sum_k A[m,k]*Bw[n,k] + bias[n] (opt gelu) ------
// m97 recipe: 128x128 tile, BK=32, 4 waves 2x2, each wave 4x4 of 16x16x32 MFMA,
// global_load_lds width=16 staging. launch_bounds(256,4): regs = 56 VGPR + 64
// AGPR acc ~= 120 <= 128, so 4 blocks/CU fit -> hide the vmcnt(0) barrier drain.
template <bool GELU, bool DYNOUT>
__global__ __launch_bounds__(256, 4)
void gemm_bt(const bf16_t* __restrict__ A, const bf16_t* __restrict__ Bw,
             const float* __restrict__ bias,
             bf16_t* __restrict__ obf, float* __restrict__ of32,
             int M, int N, int K, const int* __restrict__ flag) {
    __shared__ __attribute__((aligned(16))) bf16_t sA[128 * 32];
    __shared__ __attribute__((aligned(16))) bf16_t sB[128 * 32];

    const int tid = threadIdx.x;
    const int bm = blockIdx.y << 7;
    const int bn = blockIdx.x << 7;

    const int srow = tid >> 2;
    const int scol = (tid & 3) << 3;
    const bf16_t* gA = A + (size_t)(bm + srow) * K + scol;
    const bf16_t* gB = Bw + (size_t)(bn + srow) * K + scol;
    bf16_t* lA = sA + tid * 8;
    bf16_t* lB = sB + tid * 8;
    const size_t rowskip = (size_t)64 * K;

    const int lane = tid & 63;
    const int wave = tid >> 6;
    const int quad = lane >> 4;
    const int lr = lane & 15;
    const int wm = (wave & 1) << 6;
    const int wn = (wave >> 1) << 6;

    const bf16x8* pA = (const bf16x8*)(sA + (wm + lr) * 32 + quad * 8);
    const bf16x8* pB = (const bf16x8*)(sB + (wn + lr) * 32 + quad * 8);

    f32x4 acc[4][4] = {};

    for (int k0 = 0; k0 < K; k0 += 32) {
        g2l16(gA + k0, lA);
        g2l16(gA + rowskip + k0, lA + 2048);
        g2l16(gB + k0, lB);
        g2l16(gB + rowskip + k0, lB + 2048);
        __syncthreads();

        bf16x8 af[4], bf[4];
#pragma unroll
        for (int i = 0; i < 4; ++i) {
            af[i] = pA[i * 64];
            bf[i] = pB[i * 64];
        }
#pragma unroll
        for (int mi = 0; mi < 4; ++mi)
#pragma unroll
            for (int ni = 0; ni < 4; ++ni)
                acc[mi][ni] = __builtin_amdgcn_mfma_f32_16x16x32_bf16(
                    af[mi], bf[ni], acc[mi][ni], 0, 0, 0);
        __syncthreads();
    }

    const int outf32 = DYNOUT ? *flag : 0;
#pragma unroll
    for (int mi = 0; mi < 4; ++mi) {
#pragma unroll
        for (int ni = 0; ni < 4; ++ni) {
            const int n = bn + wn + ni * 16 + lr;
            const float bs = bias[n];
            f32x4 v = acc[mi][ni];
#pragma unroll
            for (int r = 0; r < 4; ++r) {
                const int m = bm + wm + mi * 16 + quad * 4 + r;
                float val = v[r] + bs;
                if (GELU) val = 0.5f * val * (1.0f + erff(val * 0.70710678118654752f));
                const size_t o = (size_t)m * N + n;
                if (DYNOUT) {
                    if (outf32) of32[o] = val;
                    else        obf[o] = (bf16_t)val;
                } else {
                    obf[o] = (bf16_t)val;
                }
            }
        }
    }
}

// ---------------- launch ----------------
extern "C" void kernel_launch(void* const* d_in, const int* in_sizes, int n_in,
                              void* d_out, int out_size, void* d_ws, size_t ws_size,
                              hipStream_t stream) {
    const void* x   = d_in[0];
    const void* cb1 = d_in[1];
    const int*  idx1 = (const int*)d_in[2];
    const void* b1  = d_in[3];
    const void* cb2 = d_in[4];
    const int*  idx2 = (const int*)d_in[5];
    const void* b2  = d_in[6];

    const int D = 1024, H = 4096;
    const int M = in_sizes[0] / D;     // 8192

    char* ws = (char*)d_ws;
    bf16_t* xb  = (bf16_t*)ws;                                   // M*D bf16 (16 MB)
    bf16_t* w1b = (bf16_t*)(ws + (size_t)M * D * 2);             // H*D bf16 (8 MB)
    bf16_t* hb  = (bf16_t*)((char*)w1b + (size_t)H * D * 2);     // M*H bf16 (64 MB)
    bf16_t* w2b = (bf16_t*)((char*)hb + (size_t)M * H * 2);      // D*H bf16 (8 MB)
    float*  b1f = (float*)((char*)w2b + (size_t)D * H * 2);      // H f32
    float*  b2f = b1f + H;                                       // D f32
    int*    flag = (int*)(b2f + D);

    prep_all<<<2048, 256, 0, stream>>>(x, cb1, idx1, b1, cb2, idx2, b2,
                                       xb, w1b, w2b, b1f, b2f, flag, M);

    dim3 g1(H / 128, M / 128);   // (32, 64)
    gemm_bt<true, false><<<g1, 256, 0, stream>>>(xb, w1b, b1f, hb, nullptr, M, H, D, flag);

    dim3 g2(D / 128, M / 128);   // (8, 64)
    gemm_bt<false, true><<<g2, 256, 0, stream>>>(hb, w2b, b2f, (bf16_t*)d_out, (float*)d_out, M, D, H, flag);
}

// Round 3
// 274.026 us; speedup vs baseline: 1.1034x; 1.0806x over previous
//
#include <hip/hip_runtime.h>
#include <hip/hip_bf16.h>
#include <math.h>

typedef __bf16 bf16_t;
typedef bf16_t bf16x8 __attribute__((ext_vector_type(8)));
typedef float f32x4 __attribute__((ext_vector_type(4)));

// ---------------- async global->LDS (16B per lane) ----------------
__device__ __forceinline__ void g2l16(const bf16_t* g, bf16_t* l) {
    __builtin_amdgcn_global_load_lds(
        (const __attribute__((address_space(1))) void*)g,
        (__attribute__((address_space(3))) void*)l, 16, 0, 0);
}

// ---------------- fused prep: probe + x->bf16 + dequant W1/W2 + biases ---------
__global__ void prep_all(const void* __restrict__ x,
                         const void* __restrict__ cb1, const int* __restrict__ idx1,
                         const void* __restrict__ b1,
                         const void* __restrict__ cb2, const int* __restrict__ idx2,
                         const void* __restrict__ b2,
                         bf16_t* __restrict__ xb, bf16_t* __restrict__ w1b,
                         bf16_t* __restrict__ w2b, float* __restrict__ b1f,
                         float* __restrict__ b2f, int* __restrict__ flag, int M) {
    __shared__ int s_bad;
    if (threadIdx.x == 0) s_bad = 0;
    __syncthreads();
    const unsigned short* xu = (const unsigned short*)x;
    int cnt = 0;
    for (int i = threadIdx.x; i < 8192; i += 256)
        cnt += (((xu[i] >> 7) & 0xFF) >= 0x88);
    atomicAdd(&s_bad, cnt);
    __syncthreads();
    const int f32 = (s_bad > 4);
    if (blockIdx.x == 0 && threadIdx.x == 0) flag[0] = f32;

    const int T0 = (M * 1024) / 8;
    const int T1 = 4096 * 128;
    const int T2 = 1024 * 512;
    const int TB = (4096 + 1024) / 8;
    const int total = T0 + T1 + T2 + TB;
    const int t = blockIdx.x * 256 + threadIdx.x;
    const int stride = gridDim.x * 256;

    for (int i = t; i < total; i += stride) {
        if (i < T0) {
            bf16x8 o;
            if (f32) {
                const float4* p = (const float4*)x;
                float4 a = p[2 * i], b = p[2 * i + 1];
                o[0] = (bf16_t)a.x; o[1] = (bf16_t)a.y; o[2] = (bf16_t)a.z; o[3] = (bf16_t)a.w;
                o[4] = (bf16_t)b.x; o[5] = (bf16_t)b.y; o[6] = (bf16_t)b.z; o[7] = (bf16_t)b.w;
            } else {
                o = ((const bf16x8*)x)[i];
            }
            *(bf16x8*)(xb + (size_t)i * 8) = o;
        } else if (i < T0 + T1 + T2) {
            int g2 = (i >= T0 + T1);
            int ii = g2 ? (i - T0 - T1) : (i - T0);
            int rows = g2 ? 1024 : 4096;
            int logsub = g2 ? 9 : 7;
            int sub = 1 << logsub;
            const int* idx = g2 ? idx2 : idx1;
            const void* cb = g2 ? cb2 : cb1;
            bf16_t* W = g2 ? w2b : w1b;
            int r = ii >> logsub;
            int col = (ii & (sub - 1)) << 3;
            int c = col >> logsub;
            int j = col & (sub - 1);
            int code = idx[c * rows + r];
            size_t src = ((size_t)(c * 256 + code) << logsub) + j;
            bf16x8 o;
            if (f32) {
                const float* s = (const float*)cb + src;
                float4 a = *(const float4*)s;
                float4 b = *(const float4*)(s + 4);
                o[0] = (bf16_t)a.x; o[1] = (bf16_t)a.y; o[2] = (bf16_t)a.z; o[3] = (bf16_t)a.w;
                o[4] = (bf16_t)b.x; o[5] = (bf16_t)b.y; o[6] = (bf16_t)b.z; o[7] = (bf16_t)b.w;
            } else {
                o = *(const bf16x8*)((const bf16_t*)cb + src);
            }
            *(bf16x8*)(W + (size_t)r * ((size_t)sub << 3) + col) = o;
        } else {
            int g = i - (T0 + T1 + T2);
#pragma unroll
            for (int j = 0; j < 8; ++j) {
                int e = g * 8 + j;
                float v;
                const void* src = (e < 4096) ? b1 : b2;
                int k = (e < 4096) ? e : e - 4096;
                v = f32 ? ((const float*)src)[k] : (float)(((const bf16_t*)src)[k]);
                if (e < 4096) b1f[k] = v; else b2f[k] = v;
            }
        }
    }
}

// ---------------- GEMM: C[m,n] = sum_k A[m,k]*Bw[n,k] + bias[n] (opt gelu) ------
// 128x128 tile, BK=64, 4 waves 2x2, 16x16x32 MFMA.
// XOR-swizzled LDS: slot(row,kc) = row*8 + ((kc+row)&7), kc = 8-elem chunk.
//   writer (g2l16 forces slot t <- thread t): thread t loads row=t>>3,
//   kc=((t&7)-(t>>3))&7 -- loop- and pass-invariant (32 = 0 mod 8).
//   reader: lanes (quad,lr) hit bank-group (quad+4c0+lr)&7 -> all 8 groups
//   exactly 2x per 16-lane batch = conflict-free (2-way is free, m136).
template <bool GELU, bool DYNOUT>
__global__ __launch_bounds__(256, 4)
void gemm_bt(const bf16_t* __restrict__ A, const bf16_t* __restrict__ Bw,
             const float* __restrict__ bias,
             bf16_t* __restrict__ obf, float* __restrict__ of32,
             int M, int N, int K, const int* __restrict__ flag) {
    __shared__ __attribute__((aligned(16))) bf16_t sA[128 * 64];
    __shared__ __attribute__((aligned(16))) bf16_t sB[128 * 64];

    const int tid = threadIdx.x;
    const int bm = blockIdx.y << 7;
    const int bn = blockIdx.x << 7;

    const int row0 = tid >> 3;                 // 0..31 (pass adds 32)
    const int kc0 = ((tid & 7) - row0) & 7;    // swizzle-inverted k-chunk
    const bf16_t* gA = A + (size_t)(bm + row0) * K + kc0 * 8;
    const bf16_t* gB = Bw + (size_t)(bn + row0) * K + kc0 * 8;
    bf16_t* lA = sA + tid * 8;
    bf16_t* lB = sB + tid * 8;
    const size_t pskip = (size_t)32 * K;

    const int lane = tid & 63;
    const int wave = tid >> 6;
    const int quad = lane >> 4;
    const int lr = lane & 15;
    const int wm = (wave & 1) << 6;
    const int wn = (wave >> 1) << 6;

    const int arow = wm + lr;
    const int brow = wn + lr;
    const bf16x8* pA0 = (const bf16x8*)(sA + arow * 64 + ((quad + arow) & 7) * 8);
    const bf16x8* pA1 = (const bf16x8*)(sA + arow * 64 + ((quad + 4 + arow) & 7) * 8);
    const bf16x8* pB0 = (const bf16x8*)(sB + brow * 64 + ((quad + brow) & 7) * 8);
    const bf16x8* pB1 = (const bf16x8*)(sB + brow * 64 + ((quad + 4 + brow) & 7) * 8);

    f32x4 acc[4][4] = {};

    for (int k0 = 0; k0 < K; k0 += 64) {
#pragma unroll
        for (int p = 0; p < 4; ++p) g2l16(gA + p * pskip + k0, lA + p * 2048);
#pragma unroll
        for (int p = 0; p < 4; ++p) g2l16(gB + p * pskip + k0, lB + p * 2048);
        __syncthreads();

        bf16x8 af[4], bf[4];
#pragma unroll
        for (int i = 0; i < 4; ++i) { af[i] = pA0[i * 128]; bf[i] = pB0[i * 128]; }
#pragma unroll
        for (int mi = 0; mi < 4; ++mi)
#pragma unroll
            for (int ni = 0; ni < 4; ++ni)
                acc[mi][ni] = __builtin_amdgcn_mfma_f32_16x16x32_bf16(
                    af[mi], bf[ni], acc[mi][ni], 0, 0, 0);
#pragma unroll
        for (int i = 0; i < 4; ++i) { af[i] = pA1[i * 128]; bf[i] = pB1[i * 128]; }
#pragma unroll
        for (int mi = 0; mi < 4; ++mi)
#pragma unroll
            for (int ni = 0; ni < 4; ++ni)
                acc[mi][ni] = __builtin_amdgcn_mfma_f32_16x16x32_bf16(
                    af[mi], bf[ni], acc[mi][ni], 0, 0, 0);
        __syncthreads();
    }

    const int outf32 = DYNOUT ? *flag : 0;
#pragma unroll
    for (int mi = 0; mi < 4; ++mi) {
#pragma unroll
        for (int ni = 0; ni < 4; ++ni) {
            const int n = bn + wn + ni * 16 + lr;
            const float bs = bias[n];
            f32x4 v = acc[mi][ni];
#pragma unroll
            for (int r = 0; r < 4; ++r) {
                const int m = bm + wm + mi * 16 + quad * 4 + r;
                float val = v[r] + bs;
                if (GELU) val = 0.5f * val * (1.0f + erff(val * 0.70710678118654752f));
                const size_t o = (size_t)m * N + n;
                if (DYNOUT) {
                    if (outf32) of32[o] = val;
                    else        obf[o] = (bf16_t)val;
                } else {
                    obf[o] = (bf16_t)val;
                }
            }
        }
    }
}

// ---------------- launch ----------------
extern "C" void kernel_launch(void* const* d_in, const int* in_sizes, int n_in,
                              void* d_out, int out_size, void* d_ws, size_t ws_size,
                              hipStream_t stream) {
    const void* x   = d_in[0];
    const void* cb1 = d_in[1];
    const int*  idx1 = (const int*)d_in[2];
    const void* b1  = d_in[3];
    const void* cb2 = d_in[4];
    const int*  idx2 = (const int*)d_in[5];
    const void* b2  = d_in[6];

    const int D = 1024, H = 4096;
    const int M = in_sizes[0] / D;     // 8192

    char* ws = (char*)d_ws;
    bf16_t* xb  = (bf16_t*)ws;                                   // M*D bf16 (16 MB)
    bf16_t* w1b = (bf16_t*)(ws + (size_t)M * D * 2);             // H*D bf16 (8 MB)
    bf16_t* hb  = (bf16_t*)((char*)w1b + (size_t)H * D * 2);     // M*H bf16 (64 MB)
    bf16_t* w2b = (bf16_t*)((char*)hb + (size_t)M * H * 2);      // D*H bf16 (8 MB)
    float*  b1f = (float*)((char*)w2b + (size_t)D * H * 2);      // H f32
    float*  b2f = b1f + H;                                       // D f32
    int*    flag = (int*)(b2f + D);

    prep_all<<<2048, 256, 0, stream>>>(x, cb1, idx1, b1, cb2, idx2, b2,
                                       xb, w1b, w2b, b1f, b2f, flag, M);

    dim3 g1(H / 128, M / 128);   // (32, 64)
    gemm_bt<true, false><<<g1, 256, 0, stream>>>(xb, w1b, b1f, hb, nullptr, M, H, D, flag);

    dim3 g2(D / 128, M / 128);   // (8, 64)
    gemm_bt<false, true><<<g2, 256, 0, stream>>>(hb, w2b, b2f, (bf16_t*)d_out, (float*)d_out, M, D, H, flag);
}